// Round 1
// baseline (414.606 us; speedup 1.0000x reference)
//
#include <hip/hip_runtime.h>
#include <hip/hip_bf16.h>
#include <stdint.h>

#define D_MODEL 768
#define NHEADS 12
#define HDIM 64
#define BATCH 16
#define SEQ 1024
#define MTOK (BATCH*SEQ)          // 16384
#define LOG2E 1.4426950408889634f

typedef __bf16 bfrag  __attribute__((ext_vector_type(8)));
typedef __bf16 bf16x4 __attribute__((ext_vector_type(4)));
typedef float  f32x4  __attribute__((ext_vector_type(4)));

__device__ __forceinline__ void gload16(const void* g, void* l) {
  __builtin_amdgcn_global_load_lds(
      (const __attribute__((address_space(1))) unsigned int*)g,
      (__attribute__((address_space(3))) unsigned int*)l, 16, 0, 0);
}

// ---------------- fp32 -> bf16 conversion of x and the 4 weights ------------
__global__ __launch_bounds__(256) void convert_kernel(
    const float* __restrict__ x,
    const float* __restrict__ Wq, const float* __restrict__ Wk,
    const float* __restrict__ Wv, const float* __restrict__ Wc,
    __bf16* __restrict__ xb, __bf16* __restrict__ Wb)
{
  const size_t NX = (size_t)MTOK * D_MODEL;       // 12582912
  const size_t NW = (size_t)D_MODEL * D_MODEL;    // 589824
  size_t i = ((size_t)blockIdx.x * 256 + threadIdx.x) * 4;
  const float* src; __bf16* dst; size_t off;
  if (i < NX) { src = x; dst = xb; off = i; }
  else {
    size_t wj = i - NX;
    int which = (int)(wj / NW);
    off = wj - (size_t)which * NW;
    src = which == 0 ? Wq : which == 1 ? Wk : which == 2 ? Wv : Wc;
    dst = Wb + (size_t)which * NW;
  }
  f32x4 v = *(const f32x4*)(src + off);
  bf16x4 o;
  o[0] = (__bf16)v[0]; o[1] = (__bf16)v[1]; o[2] = (__bf16)v[2]; o[3] = (__bf16)v[3];
  *(bf16x4*)(dst + off) = o;
}

// ---------------- fused QKV projection GEMM (m97 structure) -----------------
// C[m,o] = sum_k x[m,k] * W[o,k];  M=16384, N=2304 (q|k|v), K=768
__global__ __launch_bounds__(256) void qkv_gemm(
    const __bf16* __restrict__ A,   // xb [16384][768]
    const __bf16* __restrict__ W,   // Wb rows 0..2303 = q,k,v  [n][k]
    const float* __restrict__ bq, const float* __restrict__ bk, const float* __restrict__ bv,
    __bf16* __restrict__ Qb,        // [B,H,S,Dh]  pre-scaled by 0.125*log2e
    __bf16* __restrict__ Kb,        // [B,H,S,Dh]
    __bf16* __restrict__ VTb)       // [B,H,Dh,S]
{
  __shared__ __bf16 As[128 * 32];
  __shared__ __bf16 Bs[128 * 32];
  const int tid = threadIdx.x;
  const int lane = tid & 63, w = tid >> 6;
  const int wm = w >> 1, wn = w & 1;
  const int bm = blockIdx.x, bn = blockIdx.y;
  const int r4 = lane >> 2, c8 = (lane & 3) << 3;
  const int l15 = lane & 15, q8 = (lane >> 4) << 3;

  f32x4 acc[4][4];
#pragma unroll
  for (int mt = 0; mt < 4; ++mt)
#pragma unroll
    for (int nt = 0; nt < 4; ++nt) acc[mt][nt] = (f32x4){0.f, 0.f, 0.f, 0.f};

  const size_t am0 = (size_t)bm * 128;
  const size_t bn0 = (size_t)bn * 128;

  for (int kt = 0; kt < 24; ++kt) {
    const int k0 = kt * 32;
#pragma unroll
    for (int i = 0; i < 2; ++i) {
      const int rr = i * 64 + w * 16;
      gload16(A + (am0 + rr + r4) * D_MODEL + k0 + c8, &As[rr * 32]);
      gload16(W + (bn0 + rr + r4) * D_MODEL + k0 + c8, &Bs[rr * 32]);
    }
    __syncthreads();
    bfrag af[4], bf[4];
#pragma unroll
    for (int t = 0; t < 4; ++t) {
      af[t] = *(const bfrag*)&As[(wm * 64 + t * 16 + l15) * 32 + q8];
      bf[t] = *(const bfrag*)&Bs[(wn * 64 + t * 16 + l15) * 32 + q8];
    }
#pragma unroll
    for (int mt = 0; mt < 4; ++mt)
#pragma unroll
      for (int nt = 0; nt < 4; ++nt)
        acc[mt][nt] = __builtin_amdgcn_mfma_f32_16x16x32_bf16(af[mt], bf[nt], acc[mt][nt], 0, 0, 0);
    __syncthreads();
  }

  const int which = bn / 6;                 // 0=q 1=k 2=v
  const int obase = (bn % 6) * 128 + wn * 64;
  const float* bias = which == 0 ? bq : which == 1 ? bk : bv;
  const float qscale = 0.125f * LOG2E;
#pragma unroll
  for (int mt = 0; mt < 4; ++mt) {
    const int row0 = bm * 128 + wm * 64 + mt * 16 + (lane >> 4) * 4;
    const int b = row0 >> 10, s = row0 & 1023;
#pragma unroll
    for (int nt = 0; nt < 4; ++nt) {
      const int o = obase + nt * 16 + l15;
      const float bo = bias[o];
      const int h = o >> 6, d = o & 63;
      const size_t hb = ((size_t)(b * NHEADS + h)) << 16;
      if (which == 2) {
        bf16x4 pv;
#pragma unroll
        for (int r = 0; r < 4; ++r) pv[r] = (__bf16)(acc[mt][nt][r] + bo);
        *(bf16x4*)&VTb[hb + ((size_t)d << 10) + s] = pv;   // 4 consecutive s
      } else if (which == 0) {
#pragma unroll
        for (int r = 0; r < 4; ++r)
          Qb[hb + ((size_t)(s + r) << 6) + d] = (__bf16)((acc[mt][nt][r] + bo) * qscale);
      } else {
#pragma unroll
        for (int r = 0; r < 4; ++r)
          Kb[hb + ((size_t)(s + r) << 6) + d] = (__bf16)(acc[mt][nt][r] + bo);
      }
    }
  }
}

// ---------------- flash attention: per (b,h), Br=128, Bc=64 -----------------
__global__ __launch_bounds__(256) void attn_kernel(
    const __bf16* __restrict__ Qb, const __bf16* __restrict__ Kb,
    const __bf16* __restrict__ VTb, __bf16* __restrict__ ctx)
{
  __shared__ __bf16 Qs[128][72];
  __shared__ __bf16 Ks[64][72];
  __shared__ __bf16 VTs[64][72];
  __shared__ __bf16 Ps[128][72];
  const int tid = threadIdx.x, lane = tid & 63, w = tid >> 6;
  const int qt = blockIdx.x, bh = blockIdx.y;
  const int l15 = lane & 15, quad = lane >> 4, q8 = quad << 3;
  const int wrow = w * 32;
  const size_t base = (size_t)bh << 16;   // bh * S * Dh

  // stage Q tile once (kept across the KV loop)
#pragma unroll
  for (int i = 0; i < 4; ++i) {
    int g = i * 256 + tid;
    int row = g >> 3, col = (g & 7) << 3;
    *(uint4*)&Qs[row][col] = *(const uint4*)(Qb + base + (size_t)(qt * 128 + row) * 64 + col);
  }

  f32x4 Oa[2][4];
  float mst[2][4], lst[2][4];
#pragma unroll
  for (int mt = 0; mt < 2; ++mt) {
#pragma unroll
    for (int nt = 0; nt < 4; ++nt) Oa[mt][nt] = (f32x4){0.f, 0.f, 0.f, 0.f};
#pragma unroll
    for (int r = 0; r < 4; ++r) { mst[mt][r] = -3.0e38f; lst[mt][r] = 0.f; }
  }

  for (int j = 0; j < 16; ++j) {
#pragma unroll
    for (int i = 0; i < 2; ++i) {
      int g = i * 256 + tid;
      int row = g >> 3, col = (g & 7) << 3;
      *(uint4*)&Ks[row][col]  = *(const uint4*)(Kb  + base + (size_t)(j * 64 + row) * 64 + col);
      *(uint4*)&VTs[row][col] = *(const uint4*)(VTb + base + (size_t)row * 1024 + j * 64 + col);
    }
    __syncthreads();

    // S = Q K^T  (already in log2 units via Q pre-scale)
    f32x4 sacc[2][4];
    bfrag aq[2][2], bkf[4][2];
#pragma unroll
    for (int mt = 0; mt < 2; ++mt)
#pragma unroll
      for (int kk = 0; kk < 2; ++kk)
        aq[mt][kk] = *(const bfrag*)&Qs[wrow + mt * 16 + l15][kk * 32 + q8];
#pragma unroll
    for (int nt = 0; nt < 4; ++nt)
#pragma unroll
      for (int kk = 0; kk < 2; ++kk)
        bkf[nt][kk] = *(const bfrag*)&Ks[nt * 16 + l15][kk * 32 + q8];
#pragma unroll
    for (int mt = 0; mt < 2; ++mt)
#pragma unroll
      for (int nt = 0; nt < 4; ++nt) {
        sacc[mt][nt] = (f32x4){0.f, 0.f, 0.f, 0.f};
#pragma unroll
        for (int kk = 0; kk < 2; ++kk)
          sacc[mt][nt] = __builtin_amdgcn_mfma_f32_16x16x32_bf16(aq[mt][kk], bkf[nt][kk], sacc[mt][nt], 0, 0, 0);
      }

    // online softmax over this Bc=64 slab
#pragma unroll
    for (int mt = 0; mt < 2; ++mt) {
#pragma unroll
      for (int r = 0; r < 4; ++r) {
        float mx = fmaxf(fmaxf(sacc[mt][0][r], sacc[mt][1][r]),
                         fmaxf(sacc[mt][2][r], sacc[mt][3][r]));
#pragma unroll
        for (int off = 1; off < 16; off <<= 1) mx = fmaxf(mx, __shfl_xor(mx, off));
        const float mnew = fmaxf(mst[mt][r], mx);
        const float alpha = exp2f(mst[mt][r] - mnew);
        float rs = 0.f;
#pragma unroll
        for (int nt = 0; nt < 4; ++nt) {
          float p = exp2f(sacc[mt][nt][r] - mnew);
          sacc[mt][nt][r] = p;
          rs += p;
        }
#pragma unroll
        for (int off = 1; off < 16; off <<= 1) rs += __shfl_xor(rs, off);
        lst[mt][r] = lst[mt][r] * alpha + rs;
        mst[mt][r] = mnew;
#pragma unroll
        for (int nt = 0; nt < 4; ++nt) Oa[mt][nt][r] *= alpha;
      }
      // P (C-layout) -> LDS for A-layout reads
#pragma unroll
      for (int nt = 0; nt < 4; ++nt)
#pragma unroll
        for (int r = 0; r < 4; ++r)
          Ps[wrow + mt * 16 + quad * 4 + r][nt * 16 + l15] = (__bf16)sacc[mt][nt][r];
    }
    __syncthreads();

    // O += P V
    bfrag ap[2][2], bvf[4][2];
#pragma unroll
    for (int mt = 0; mt < 2; ++mt)
#pragma unroll
      for (int kk = 0; kk < 2; ++kk)
        ap[mt][kk] = *(const bfrag*)&Ps[wrow + mt * 16 + l15][kk * 32 + q8];
#pragma unroll
    for (int nt = 0; nt < 4; ++nt)
#pragma unroll
      for (int kk = 0; kk < 2; ++kk)
        bvf[nt][kk] = *(const bfrag*)&VTs[nt * 16 + l15][kk * 32 + q8];
#pragma unroll
    for (int mt = 0; mt < 2; ++mt)
#pragma unroll
      for (int nt = 0; nt < 4; ++nt)
#pragma unroll
        for (int kk = 0; kk < 2; ++kk)
          Oa[mt][nt] = __builtin_amdgcn_mfma_f32_16x16x32_bf16(ap[mt][kk], bvf[nt][kk], Oa[mt][nt], 0, 0, 0);
    __syncthreads();
  }

  // epilogue: ctx[b, s, h*64+d] = O / l
  const int b = bh / NHEADS, h = bh - b * NHEADS;
#pragma unroll
  for (int mt = 0; mt < 2; ++mt)
#pragma unroll
    for (int r = 0; r < 4; ++r) {
      const int row = wrow + mt * 16 + quad * 4 + r;
      const int s = qt * 128 + row;
      const float inv = 1.0f / lst[mt][r];
#pragma unroll
      for (int nt = 0; nt < 4; ++nt) {
        const int d = nt * 16 + l15;
        ctx[((size_t)(b * SEQ + s)) * D_MODEL + h * HDIM + d] = (__bf16)(Oa[mt][nt][r] * inv);
      }
    }
}

// ---------------- output projection: out = ctx @ Wc^T + bc (fp32 out) -------
__global__ __launch_bounds__(256) void out_gemm(
    const __bf16* __restrict__ A,   // ctx [16384][768]
    const __bf16* __restrict__ W,   // Wc bf16 [768][768] (n,k)
    const float* __restrict__ bc,
    float* __restrict__ out)
{
  __shared__ __bf16 As[128 * 32];
  __shared__ __bf16 Bs[128 * 32];
  const int tid = threadIdx.x;
  const int lane = tid & 63, w = tid >> 6;
  const int wm = w >> 1, wn = w & 1;
  const int bm = blockIdx.x, bn = blockIdx.y;
  const int r4 = lane >> 2, c8 = (lane & 3) << 3;
  const int l15 = lane & 15, q8 = (lane >> 4) << 3;

  f32x4 acc[4][4];
#pragma unroll
  for (int mt = 0; mt < 4; ++mt)
#pragma unroll
    for (int nt = 0; nt < 4; ++nt) acc[mt][nt] = (f32x4){0.f, 0.f, 0.f, 0.f};

  const size_t am0 = (size_t)bm * 128;
  const size_t bn0 = (size_t)bn * 128;

  for (int kt = 0; kt < 24; ++kt) {
    const int k0 = kt * 32;
#pragma unroll
    for (int i = 0; i < 2; ++i) {
      const int rr = i * 64 + w * 16;
      gload16(A + (am0 + rr + r4) * D_MODEL + k0 + c8, &As[rr * 32]);
      gload16(W + (bn0 + rr + r4) * D_MODEL + k0 + c8, &Bs[rr * 32]);
    }
    __syncthreads();
    bfrag af[4], bf[4];
#pragma unroll
    for (int t = 0; t < 4; ++t) {
      af[t] = *(const bfrag*)&As[(wm * 64 + t * 16 + l15) * 32 + q8];
      bf[t] = *(const bfrag*)&Bs[(wn * 64 + t * 16 + l15) * 32 + q8];
    }
#pragma unroll
    for (int mt = 0; mt < 4; ++mt)
#pragma unroll
      for (int nt = 0; nt < 4; ++nt)
        acc[mt][nt] = __builtin_amdgcn_mfma_f32_16x16x32_bf16(af[mt], bf[nt], acc[mt][nt], 0, 0, 0);
    __syncthreads();
  }

#pragma unroll
  for (int mt = 0; mt < 4; ++mt) {
    const int row0 = bm * 128 + wm * 64 + mt * 16 + (lane >> 4) * 4;
#pragma unroll
    for (int nt = 0; nt < 4; ++nt) {
      const int o = bn * 128 + wn * 64 + nt * 16 + l15;
      const float bo = bc[o];
#pragma unroll
      for (int r = 0; r < 4; ++r)
        out[(size_t)(row0 + r) * D_MODEL + o] = acc[mt][nt][r] + bo;
    }
  }
}

// ---------------- launcher --------------------------------------------------
extern "C" void kernel_launch(void* const* d_in, const int* in_sizes, int n_in,
                              void* d_out, int out_size, void* d_ws, size_t ws_size,
                              hipStream_t stream)
{
  const float* x  = (const float*)d_in[0];
  const float* Wq = (const float*)d_in[1];
  const float* bq = (const float*)d_in[2];
  const float* Wk = (const float*)d_in[3];
  const float* bk = (const float*)d_in[4];
  const float* Wv = (const float*)d_in[5];
  const float* bv = (const float*)d_in[6];
  const float* Wc = (const float*)d_in[7];
  const float* bc = (const float*)d_in[8];
  float* out = (float*)d_out;

  // workspace layout (bytes):
  //   xb  @ 0          : 25165824   (aliased as ctx after qkv_gemm is done)
  //   Wb  @ 25165824   : 4718592    (q,k,v,c bf16 weights, [n][k])
  //   Qb  @ 29884416   : 25165824   [B,H,S,Dh] (pre-scaled)
  //   Kb  @ 55050240   : 25165824   [B,H,S,Dh]
  //   VTb @ 80216064   : 25165824   [B,H,Dh,S]
  //   total 105381888
  char* ws = (char*)d_ws;
  __bf16* xb  = (__bf16*)(ws);
  __bf16* Wb  = (__bf16*)(ws + 25165824);
  __bf16* Qb  = (__bf16*)(ws + 29884416);
  __bf16* Kb  = (__bf16*)(ws + 55050240);
  __bf16* VTb = (__bf16*)(ws + 80216064);
  __bf16* ctx = xb;   // safe: qkv_gemm (last reader of xb) completes before attn writes

  convert_kernel<<<14592, 256, 0, stream>>>(x, Wq, Wk, Wv, Wc, xb, Wb);
  qkv_gemm<<<dim3(128, 18), 256, 0, stream>>>(xb, Wb, bq, bk, bv, Qb, Kb, VTb);
  attn_kernel<<<dim3(8, 192), 256, 0, stream>>>(Qb, Kb, VTb, ctx);
  out_gemm<<<dim3(128, 6), 256, 0, stream>>>(ctx, Wb + 3 * 589824, bc, out);
}